// Round 2
// baseline (377.823 us; speedup 1.0000x reference)
//
#include <hip/hip_runtime.h>
#include <math.h>

// ConvTranspose2d(64,64,k4,s2,p1) + bias + mish + 0.5 clamp[-1,1] *2, via MFMA.
// Quadrant decomposition: output parity (r,s) -> 2x2 stride-1 conv.
// GEMM per (n,y,quadrant): M=64 oc, N=64 x-pos, K=256=(j,kk)x64ic.
// v5: v3 structure (rolling 4-slot LDS row ring, register prefetch, scatter
// stores that merge in L2 across s-parity waves) BUT the per-iy sync is a raw
// s_barrier + lgkmcnt(0) only -- global stores and prefetch loads stay in
// flight across the barrier instead of draining vmcnt(0) every iteration.

typedef __attribute__((ext_vector_type(8))) short bf16x8;
typedef __attribute__((ext_vector_type(4))) float floatx4;

#define LDS_ROW 4224   // 66 cols * 64 ic (ushort units)

__device__ __forceinline__ unsigned short f2bf(float f) {
    unsigned int u = __float_as_uint(f);
    u += 0x7fffu + ((u >> 16) & 1u);
    return (unsigned short)(u >> 16);
}

__device__ __forceinline__ unsigned long long pack4(unsigned short a, unsigned short b,
                                                    unsigned short c, unsigned short d) {
    return (unsigned long long)a | ((unsigned long long)b << 16) |
           ((unsigned long long)c << 32) | ((unsigned long long)d << 48);
}

__device__ __forceinline__ float act(float y) {
    // mish(y) = y*tanh(softplus(y)); tanh(ln(1+e)) = (e^2+2e)/(e^2+2e+2)
    // lower clamp never binds (mish+0.5 >= 0.19); y>8 saturates upper clamp.
    float t = fminf(y, 8.f);
    float e = __expf(t);
    float p = e * (e + 2.f);
    float m = t * p * __builtin_amdgcn_rcpf(p + 2.f);
    float v = fminf(m + 0.5f, 1.f);
    return v + v;
}

// LDS-visibility-only barrier: ring protocol needs ds ops ordered across it,
// but global stores (never read back) and wave-private prefetch loads may
// remain in flight. __syncthreads() would drain vmcnt(0) and serialize the
// store queue against compute every iteration.
__device__ __forceinline__ void ring_barrier() {
    asm volatile("s_waitcnt lgkmcnt(0)" ::: "memory");
    __builtin_amdgcn_s_barrier();
}

__global__ __launch_bounds__(256, 2) void convt_mfma5(
    const float* __restrict__ x, const float* __restrict__ w,
    const float* __restrict__ bias, float* __restrict__ out)
{
    __shared__ unsigned short lds[16896];   // 33 KB: 4-slot row ring (+weight scratch)

    const int tid  = threadIdx.x;
    const int lane = tid & 63;
    const int wid  = tid >> 6;
    const int r = wid >> 1, s = wid & 1;        // quadrant
    const int q = lane >> 4, mcol = lane & 15;  // MFMA lane decomposition

    const int bid = blockIdx.x;
    const int n   = bid >> 3;
    const int y0  = (bid & 7) * 8;

    const float* xn = x + (size_t)n * 262144;   // 64*64*64

    // ---------------- stage weights -> persistent A fragments ----------------
    bf16x8 a[4][8];
    {
        const int tap = tid & 15;
        const int icq = tid >> 4;
        const int icw = icq * 4;
        for (int c = 0; c < 4; ++c) {
            __syncthreads();
            #pragma unroll
            for (int it = 0; it < 16; ++it) {
                const float* wp = w + ((16 * c + it) * 1024 + icw * 16 + tap);
                unsigned long long pk = pack4(f2bf(wp[0]), f2bf(wp[16]),
                                              f2bf(wp[32]), f2bf(wp[48]));
                *(unsigned long long*)&lds[(it * 16 + tap) * 64 + (icw ^ ((tap & 7) * 8))] = pk;
            }
            __syncthreads();
            #pragma unroll
            for (int ks = 0; ks < 8; ++ks) {
                const int tl = ks >> 1;
                const int j = tl >> 1, kk = tl & 1;
                const int kh = 3 - r - 2 * j, kw = 3 - s - 2 * kk;
                const int tapidx = kh * 4 + kw;
                const int ic0 = (ks & 1) * 32 + q * 8;
                a[c][ks] = *(const bf16x8*)&lds[(mcol * 16 + tapidx) * 64 +
                                                (ic0 ^ ((tapidx & 7) * 8))];
            }
        }
    }

    float bv[4][4];
    #pragma unroll
    for (int mt = 0; mt < 4; ++mt)
        #pragma unroll
        for (int rg = 0; rg < 4; ++rg)
            bv[mt][rg] = bias[mt * 16 + q * 4 + rg];

    __syncthreads();   // a-frag reads done; lds becomes the x row ring

    // staging thread mapping: 4 cols x 4 ic per thread
    const int colg = tid & 15, icg = tid >> 4;
    const int c0 = colg * 4, ic0s = icg * 4;

    auto write_row = [&](int slot, const float4& v0, const float4& v1,
                         const float4& v2, const float4& v3) {
        #pragma unroll
        for (int k = 0; k < 4; ++k) {
            const int cp = c0 + k + 1;
            unsigned long long pk = pack4(f2bf((&v0.x)[k]), f2bf((&v1.x)[k]),
                                          f2bf((&v2.x)[k]), f2bf((&v3.x)[k]));
            *(unsigned long long*)&lds[slot * LDS_ROW + cp * 64 +
                                       (ic0s ^ ((cp & 7) * 8))] = pk;
        }
    };
    auto load_row = [&](int ry, float4& v0, float4& v1, float4& v2, float4& v3) {
        const float* xp = xn + (size_t)ic0s * 4096 + ry * 64 + c0;
        v0 = *(const float4*)(xp);
        v1 = *(const float4*)(xp + 4096);
        v2 = *(const float4*)(xp + 8192);
        v3 = *(const float4*)(xp + 12288);
    };
    const float4 z4 = {0.f, 0.f, 0.f, 0.f};

    // halo cols (cp=0,65) are zero for every row: zero once, all 4 slots
    if (tid < 64) {
        const int slot = tid >> 4;
        const int cpz  = ((tid >> 3) & 1) ? 65 : 0;
        const int part = tid & 7;   // 8 ushorts each
        unsigned long long* p =
            (unsigned long long*)&lds[slot * LDS_ROW + cpz * 64 + part * 8];
        p[0] = 0ULL; p[1] = 0ULL;
    }

    // prologue: rows y0-1, y0, y0+1 -> slots 0,1,2
    #pragma unroll
    for (int pr = 0; pr < 3; ++pr) {
        const int ry = y0 - 1 + pr;
        float4 v0 = z4, v1 = z4, v2 = z4, v3 = z4;
        if (ry >= 0 && ry < 64) load_row(ry, v0, v1, v2, v3);
        write_row(pr, v0, v1, v2, v3);
    }

    // per-thread output base: oc base = q*4, oh base = r, ow base = s + 2*mcol
    float* ob0 = out + (size_t)n * 1048576 + (size_t)(q * 4) * 16384 +
                 (size_t)r * 128 + (size_t)(s + 2 * mcol);

    for (int iy = 0; iy < 8; ++iy) {
        const int y = y0 + iy;
        ring_barrier();   // ring writes visible; prev iter's reads done.
                          // stores + loads stay in flight.

        // prefetch next row into registers (consumed at end of this iter)
        const int ry_pf = y + 2;
        const bool pf_valid = (iy < 7) && (ry_pf < 64);
        float4 p0 = z4, p1 = z4, p2 = z4, p3 = z4;
        if (pf_valid) load_row(ry_pf, p0, p1, p2, p3);

        // ---- MFMA compute for output row pair at y ----
        floatx4 acc[4][4];
        #pragma unroll
        for (int mt = 0; mt < 4; ++mt)
            #pragma unroll
            for (int nt = 0; nt < 4; ++nt)
                acc[mt][nt] = (floatx4){0.f, 0.f, 0.f, 0.f};

        #pragma unroll
        for (int ks = 0; ks < 8; ++ks) {
            const int tl = ks >> 1;
            const int j = tl >> 1, kk = tl & 1;
            const int slotj = (iy + r + j) & 3;         // row y-1+r+j
            const int icb = (ks & 1) * 32 + q * 8;
            bf16x8 b[4];
            #pragma unroll
            for (int nt = 0; nt < 4; ++nt) {
                const int cp = nt * 16 + mcol + kk + s;
                b[nt] = *(const bf16x8*)&lds[slotj * LDS_ROW + cp * 64 +
                                             (icb ^ ((cp & 7) * 8))];
            }
            #pragma unroll
            for (int mt = 0; mt < 4; ++mt)
                #pragma unroll
                for (int nt = 0; nt < 4; ++nt)
                    acc[mt][nt] = __builtin_amdgcn_mfma_f32_16x16x32_bf16(
                        a[mt][ks], b[nt], acc[mt][nt], 0, 0, 0);
        }

        // ---- epilogue: scatter dword stores (merge to full lines in L2
        // across the s-parity waves); constant offsets off per-thread base ----
        {
            float* op = ob0 + (size_t)(2 * y) * 128;
            #pragma unroll
            for (int mt = 0; mt < 4; ++mt)
                #pragma unroll
                for (int nt = 0; nt < 4; ++nt)
                    #pragma unroll
                    for (int rg = 0; rg < 4; ++rg)
                        op[mt * 262144 + rg * 16384 + nt * 32] =
                            act(acc[mt][nt][rg] + bv[mt][rg]);
        }

        // ---- convert prefetch regs, write row y+2 into ring ----
        if (iy < 7) {
            write_row((iy + 3) & 3, p0, p1, p2, p3);
        }
    }
}

extern "C" void kernel_launch(void* const* d_in, const int* in_sizes, int n_in,
                              void* d_out, int out_size, void* d_ws, size_t ws_size,
                              hipStream_t stream) {
    const float* x    = (const float*)d_in[0];
    const float* wgt  = (const float*)d_in[1];
    const float* bias = (const float*)d_in[2];
    float* out = (float*)d_out;

    convt_mfma5<<<dim3(512), dim3(256), 0, stream>>>(x, wgt, bias, out);
}

// Round 3
// 368.575 us; speedup vs baseline: 1.0251x; 1.0251x over previous
//
#include <hip/hip_runtime.h>
#include <math.h>

// ConvTranspose2d(64,64,k4,s2,p1) + bias + mish + 0.5 clamp[-1,1] *2, via MFMA.
// Quadrant decomposition: output parity (r,s) -> 2x2 stride-1 conv.
// GEMM per (n,y,quadrant): M=64 oc, N=64 x-pos, K=256=(j,kk)x64ic.
// v6: intra-wave pipe interleave. Each iy is split into two mt-halves
// (MFMA half -> epilogue half -> ring-write -> MFMA half -> epilogue half)
// so stores/VALU/MFMA run concurrently from one wave's stream instead of
// taking turns. acc liveness halves (2x4 per half); b-frags re-read per half
// (LDS has capacity to spare vs the HBM pipe). Barriers stay lgkm-only (v5).

typedef __attribute__((ext_vector_type(8))) short bf16x8;
typedef __attribute__((ext_vector_type(4))) float floatx4;

#define LDS_ROW 4224   // 66 cols * 64 ic (ushort units)

__device__ __forceinline__ unsigned short f2bf(float f) {
    unsigned int u = __float_as_uint(f);
    u += 0x7fffu + ((u >> 16) & 1u);
    return (unsigned short)(u >> 16);
}

__device__ __forceinline__ unsigned long long pack4(unsigned short a, unsigned short b,
                                                    unsigned short c, unsigned short d) {
    return (unsigned long long)a | ((unsigned long long)b << 16) |
           ((unsigned long long)c << 32) | ((unsigned long long)d << 48);
}

__device__ __forceinline__ float act(float y) {
    // mish(y) = y*tanh(softplus(y)); tanh(ln(1+e)) = (e^2+2e)/(e^2+2e+2)
    // lower clamp never binds (mish+0.5 >= 0.19); y>8 saturates upper clamp.
    float t = fminf(y, 8.f);
    float e = __expf(t);
    float p = e * (e + 2.f);
    float m = t * p * __builtin_amdgcn_rcpf(p + 2.f);
    float v = fminf(m + 0.5f, 1.f);
    return v + v;
}

// LDS-visibility-only barrier: ring protocol needs ds ops ordered across it;
// global stores (never read back) and wave-private prefetch loads stay in
// flight across it.
__device__ __forceinline__ void ring_barrier() {
    asm volatile("s_waitcnt lgkmcnt(0)" ::: "memory");
    __builtin_amdgcn_s_barrier();
}

__global__ __launch_bounds__(256, 2) void convt_mfma6(
    const float* __restrict__ x, const float* __restrict__ w,
    const float* __restrict__ bias, float* __restrict__ out)
{
    __shared__ unsigned short lds[16896];   // 33 KB: 4-slot row ring (+weight scratch)

    const int tid  = threadIdx.x;
    const int lane = tid & 63;
    const int wid  = tid >> 6;
    const int r = wid >> 1, s = wid & 1;        // quadrant
    const int q = lane >> 4, mcol = lane & 15;  // MFMA lane decomposition

    const int bid = blockIdx.x;
    const int n   = bid >> 3;
    const int y0  = (bid & 7) * 8;

    const float* xn = x + (size_t)n * 262144;   // 64*64*64

    // ---------------- stage weights -> persistent A fragments ----------------
    bf16x8 a[4][8];
    {
        const int tap = tid & 15;
        const int icq = tid >> 4;
        const int icw = icq * 4;
        for (int c = 0; c < 4; ++c) {
            __syncthreads();
            #pragma unroll
            for (int it = 0; it < 16; ++it) {
                const float* wp = w + ((16 * c + it) * 1024 + icw * 16 + tap);
                unsigned long long pk = pack4(f2bf(wp[0]), f2bf(wp[16]),
                                              f2bf(wp[32]), f2bf(wp[48]));
                *(unsigned long long*)&lds[(it * 16 + tap) * 64 + (icw ^ ((tap & 7) * 8))] = pk;
            }
            __syncthreads();
            #pragma unroll
            for (int ks = 0; ks < 8; ++ks) {
                const int tl = ks >> 1;
                const int j = tl >> 1, kk = tl & 1;
                const int kh = 3 - r - 2 * j, kw = 3 - s - 2 * kk;
                const int tapidx = kh * 4 + kw;
                const int ic0 = (ks & 1) * 32 + q * 8;
                a[c][ks] = *(const bf16x8*)&lds[(mcol * 16 + tapidx) * 64 +
                                                (ic0 ^ ((tapidx & 7) * 8))];
            }
        }
    }

    float bv[4][4];
    #pragma unroll
    for (int mt = 0; mt < 4; ++mt)
        #pragma unroll
        for (int rg = 0; rg < 4; ++rg)
            bv[mt][rg] = bias[mt * 16 + q * 4 + rg];

    __syncthreads();   // a-frag reads done; lds becomes the x row ring

    // staging thread mapping: 4 cols x 4 ic per thread
    const int colg = tid & 15, icg = tid >> 4;
    const int c0 = colg * 4, ic0s = icg * 4;

    auto write_row = [&](int slot, const float4& v0, const float4& v1,
                         const float4& v2, const float4& v3) {
        #pragma unroll
        for (int k = 0; k < 4; ++k) {
            const int cp = c0 + k + 1;
            unsigned long long pk = pack4(f2bf((&v0.x)[k]), f2bf((&v1.x)[k]),
                                          f2bf((&v2.x)[k]), f2bf((&v3.x)[k]));
            *(unsigned long long*)&lds[slot * LDS_ROW + cp * 64 +
                                       (ic0s ^ ((cp & 7) * 8))] = pk;
        }
    };
    auto load_row = [&](int ry, float4& v0, float4& v1, float4& v2, float4& v3) {
        const float* xp = xn + (size_t)ic0s * 4096 + ry * 64 + c0;
        v0 = *(const float4*)(xp);
        v1 = *(const float4*)(xp + 4096);
        v2 = *(const float4*)(xp + 8192);
        v3 = *(const float4*)(xp + 12288);
    };
    const float4 z4 = {0.f, 0.f, 0.f, 0.f};

    // halo cols (cp=0,65) are zero for every row: zero once, all 4 slots
    if (tid < 64) {
        const int slot = tid >> 4;
        const int cpz  = ((tid >> 3) & 1) ? 65 : 0;
        const int part = tid & 7;   // 8 ushorts each
        unsigned long long* p =
            (unsigned long long*)&lds[slot * LDS_ROW + cpz * 64 + part * 8];
        p[0] = 0ULL; p[1] = 0ULL;
    }

    // prologue: rows y0-1, y0, y0+1 -> slots 0,1,2
    #pragma unroll
    for (int pr = 0; pr < 3; ++pr) {
        const int ry = y0 - 1 + pr;
        float4 v0 = z4, v1 = z4, v2 = z4, v3 = z4;
        if (ry >= 0 && ry < 64) load_row(ry, v0, v1, v2, v3);
        write_row(pr, v0, v1, v2, v3);
    }

    // per-thread output base: oc base = q*4, oh base = r, ow base = s + 2*mcol
    float* ob0 = out + (size_t)n * 1048576 + (size_t)(q * 4) * 16384 +
                 (size_t)r * 128 + (size_t)(s + 2 * mcol);

    for (int iy = 0; iy < 8; ++iy) {
        const int y = y0 + iy;
        ring_barrier();   // ring writes visible; prev iter's reads done.
                          // stores + loads stay in flight.

        // prefetch next row: issue now, consumed at mid-iy write_row
        const int ry_pf = y + 2;
        const bool pf_valid = (iy < 7) && (ry_pf < 64);
        float4 p0 = z4, p1 = z4, p2 = z4, p3 = z4;
        if (pf_valid) load_row(ry_pf, p0, p1, p2, p3);

        float* op = ob0 + (size_t)(2 * y) * 128;

        #pragma unroll
        for (int half = 0; half < 2; ++half) {
            floatx4 acc[2][4];
            #pragma unroll
            for (int mt2 = 0; mt2 < 2; ++mt2)
                #pragma unroll
                for (int nt = 0; nt < 4; ++nt)
                    acc[mt2][nt] = (floatx4){0.f, 0.f, 0.f, 0.f};

            #pragma unroll
            for (int ks = 0; ks < 8; ++ks) {
                const int tl = ks >> 1;
                const int j = tl >> 1, kk = tl & 1;
                const int slotj = (iy + r + j) & 3;         // row y-1+r+j
                const int icb = (ks & 1) * 32 + q * 8;
                bf16x8 b[4];
                #pragma unroll
                for (int nt = 0; nt < 4; ++nt) {
                    const int cp = nt * 16 + mcol + kk + s;
                    b[nt] = *(const bf16x8*)&lds[slotj * LDS_ROW + cp * 64 +
                                                 (icb ^ ((cp & 7) * 8))];
                }
                #pragma unroll
                for (int mt2 = 0; mt2 < 2; ++mt2) {
                    const int mt = half * 2 + mt2;
                    #pragma unroll
                    for (int nt = 0; nt < 4; ++nt)
                        acc[mt2][nt] = __builtin_amdgcn_mfma_f32_16x16x32_bf16(
                            a[mt][ks], b[nt], acc[mt2][nt], 0, 0, 0);
                }
            }

            // epilogue for this mt-pair: stores start draining while the
            // other half's MFMA work is still ahead in program order
            #pragma unroll
            for (int mt2 = 0; mt2 < 2; ++mt2) {
                const int mt = half * 2 + mt2;
                #pragma unroll
                for (int nt = 0; nt < 4; ++nt)
                    #pragma unroll
                    for (int rg = 0; rg < 4; ++rg)
                        op[mt * 262144 + rg * 16384 + nt * 32] =
                            act(acc[mt2][nt][rg] + bv[mt][rg]);
            }

            // ring update mid-iy: spreads LDS writes; prefetch loads have had
            // ~half an iy (>> HBM latency) to land
            if (half == 0 && iy < 7)
                write_row((iy + 3) & 3, p0, p1, p2, p3);
        }
    }
}

extern "C" void kernel_launch(void* const* d_in, const int* in_sizes, int n_in,
                              void* d_out, int out_size, void* d_ws, size_t ws_size,
                              hipStream_t stream) {
    const float* x    = (const float*)d_in[0];
    const float* wgt  = (const float*)d_in[1];
    const float* bias = (const float*)d_in[2];
    float* out = (float*)d_out;

    convt_mfma6<<<dim3(512), dim3(256), 0, stream>>>(x, wgt, bias, out);
}

// Round 4
// 335.443 us; speedup vs baseline: 1.1263x; 1.0988x over previous
//
#include <hip/hip_runtime.h>
#include <math.h>

// ConvTranspose2d(64,64,k4,s2,p1) + bias + mish + 0.5 clamp[-1,1] *2, via MFMA.
// Quadrant decomposition: output parity (r,s) -> 2x2 stride-1 conv.
// GEMM per (n,y,quadrant): M=64 oc, N=64 x-pos, K=256=(j,kk)x64ic.
// v7: nt-level interleave. Inner loop is per output-column-tile nt: each ks
// reads ONE b-fragment consumed by all 4 mt MFMAs (b-reads back to 32/wave/iy,
// half of v6), acc liveness 16 regs, and epilogue stores + ring-write chunks
// are emitted at 4 points per iy between independent MFMA groups so the
// store/VALU/MFMA pipes stay concurrently fed. Barriers stay lgkm-only (v5).

typedef __attribute__((ext_vector_type(8))) short bf16x8;
typedef __attribute__((ext_vector_type(4))) float floatx4;

#define LDS_ROW 4224   // 66 cols * 64 ic (ushort units)

__device__ __forceinline__ unsigned short f2bf(float f) {
    unsigned int u = __float_as_uint(f);
    u += 0x7fffu + ((u >> 16) & 1u);
    return (unsigned short)(u >> 16);
}

__device__ __forceinline__ unsigned long long pack4(unsigned short a, unsigned short b,
                                                    unsigned short c, unsigned short d) {
    return (unsigned long long)a | ((unsigned long long)b << 16) |
           ((unsigned long long)c << 32) | ((unsigned long long)d << 48);
}

__device__ __forceinline__ float act(float y) {
    // mish(y) = y*tanh(softplus(y)); tanh(ln(1+e)) = (e^2+2e)/(e^2+2e+2)
    // result = clamp(mish+0.5,-1,1)*2 = min(2m+1, 2); lower clamp never binds
    // (mish+0.5 >= 0.19); y>8 saturates the upper clamp.
    float t = fminf(y, 8.f);
    float e = __expf(t);
    float p = e * (e + 2.f);
    float m = t * p * __builtin_amdgcn_rcpf(p + 2.f);
    return fminf(fmaf(m, 2.f, 1.f), 2.f);
}

// LDS-visibility-only barrier: ring protocol needs ds ops ordered across it;
// global stores (never read back) and wave-private prefetch loads stay in
// flight across it.
__device__ __forceinline__ void ring_barrier() {
    asm volatile("s_waitcnt lgkmcnt(0)" ::: "memory");
    __builtin_amdgcn_s_barrier();
}

__global__ __launch_bounds__(256, 2) void convt_mfma7(
    const float* __restrict__ x, const float* __restrict__ w,
    const float* __restrict__ bias, float* __restrict__ out)
{
    __shared__ unsigned short lds[16896];   // 33 KB: 4-slot row ring (+weight scratch)

    const int tid  = threadIdx.x;
    const int lane = tid & 63;
    const int wid  = tid >> 6;
    const int r = wid >> 1, s = wid & 1;        // quadrant
    const int q = lane >> 4, mcol = lane & 15;  // MFMA lane decomposition

    const int bid = blockIdx.x;
    const int n   = bid >> 3;
    const int y0  = (bid & 7) * 8;

    const float* xn = x + (size_t)n * 262144;   // 64*64*64

    // ---------------- stage weights -> persistent A fragments ----------------
    bf16x8 a[4][8];
    {
        const int tap = tid & 15;
        const int icq = tid >> 4;
        const int icw = icq * 4;
        for (int c = 0; c < 4; ++c) {
            __syncthreads();
            #pragma unroll
            for (int it = 0; it < 16; ++it) {
                const float* wp = w + ((16 * c + it) * 1024 + icw * 16 + tap);
                unsigned long long pk = pack4(f2bf(wp[0]), f2bf(wp[16]),
                                              f2bf(wp[32]), f2bf(wp[48]));
                *(unsigned long long*)&lds[(it * 16 + tap) * 64 + (icw ^ ((tap & 7) * 8))] = pk;
            }
            __syncthreads();
            #pragma unroll
            for (int ks = 0; ks < 8; ++ks) {
                const int tl = ks >> 1;
                const int j = tl >> 1, kk = tl & 1;
                const int kh = 3 - r - 2 * j, kw = 3 - s - 2 * kk;
                const int tapidx = kh * 4 + kw;
                const int ic0 = (ks & 1) * 32 + q * 8;
                a[c][ks] = *(const bf16x8*)&lds[(mcol * 16 + tapidx) * 64 +
                                                (ic0 ^ ((tapidx & 7) * 8))];
            }
        }
    }

    float bv[4][4];
    #pragma unroll
    for (int mt = 0; mt < 4; ++mt)
        #pragma unroll
        for (int rg = 0; rg < 4; ++rg)
            bv[mt][rg] = bias[mt * 16 + q * 4 + rg];

    __syncthreads();   // a-frag reads done; lds becomes the x row ring

    // staging thread mapping: 4 cols x 4 ic per thread
    const int colg = tid & 15, icg = tid >> 4;
    const int c0 = colg * 4, ic0s = icg * 4;

    auto write_row = [&](int slot, const float4& v0, const float4& v1,
                         const float4& v2, const float4& v3) {
        #pragma unroll
        for (int k = 0; k < 4; ++k) {
            const int cp = c0 + k + 1;
            unsigned long long pk = pack4(f2bf((&v0.x)[k]), f2bf((&v1.x)[k]),
                                          f2bf((&v2.x)[k]), f2bf((&v3.x)[k]));
            *(unsigned long long*)&lds[slot * LDS_ROW + cp * 64 +
                                       (ic0s ^ ((cp & 7) * 8))] = pk;
        }
    };
    // half of a ring-row write: columns k0, k0+1 (spreads ds_writes across
    // two interleave points in the iy loop)
    auto write_row_half = [&](int slot, int k0, const float4& v0, const float4& v1,
                              const float4& v2, const float4& v3) {
        #pragma unroll
        for (int k2 = 0; k2 < 2; ++k2) {
            const int k = k0 + k2;
            const int cp = c0 + k + 1;
            unsigned long long pk = pack4(f2bf((&v0.x)[k]), f2bf((&v1.x)[k]),
                                          f2bf((&v2.x)[k]), f2bf((&v3.x)[k]));
            *(unsigned long long*)&lds[slot * LDS_ROW + cp * 64 +
                                       (ic0s ^ ((cp & 7) * 8))] = pk;
        }
    };
    auto load_row = [&](int ry, float4& v0, float4& v1, float4& v2, float4& v3) {
        const float* xp = xn + (size_t)ic0s * 4096 + ry * 64 + c0;
        v0 = *(const float4*)(xp);
        v1 = *(const float4*)(xp + 4096);
        v2 = *(const float4*)(xp + 8192);
        v3 = *(const float4*)(xp + 12288);
    };
    const float4 z4 = {0.f, 0.f, 0.f, 0.f};

    // halo cols (cp=0,65) are zero for every row: zero once, all 4 slots
    if (tid < 64) {
        const int slot = tid >> 4;
        const int cpz  = ((tid >> 3) & 1) ? 65 : 0;
        const int part = tid & 7;   // 8 ushorts each
        unsigned long long* p =
            (unsigned long long*)&lds[slot * LDS_ROW + cpz * 64 + part * 8];
        p[0] = 0ULL; p[1] = 0ULL;
    }

    // prologue: rows y0-1, y0, y0+1 -> slots 0,1,2
    #pragma unroll
    for (int pr = 0; pr < 3; ++pr) {
        const int ry = y0 - 1 + pr;
        float4 v0 = z4, v1 = z4, v2 = z4, v3 = z4;
        if (ry >= 0 && ry < 64) load_row(ry, v0, v1, v2, v3);
        write_row(pr, v0, v1, v2, v3);
    }

    // per-thread output base: oc base = q*4, oh base = r, ow base = s + 2*mcol
    float* ob0 = out + (size_t)n * 1048576 + (size_t)(q * 4) * 16384 +
                 (size_t)r * 128 + (size_t)(s + 2 * mcol);

    for (int iy = 0; iy < 8; ++iy) {
        const int y = y0 + iy;
        ring_barrier();   // ring writes visible; prev iter's reads done.
                          // stores + loads stay in flight.

        // prefetch next row: issue now, consumed at the nt=1/nt=2 ring writes
        const int ry_pf = y + 2;
        const bool pf_valid = (iy < 7) && (ry_pf < 64);
        float4 p0 = z4, p1 = z4, p2 = z4, p3 = z4;
        if (pf_valid) load_row(ry_pf, p0, p1, p2, p3);

        float* op = ob0 + (size_t)(2 * y) * 128;

        #pragma unroll
        for (int nt = 0; nt < 4; ++nt) {
            floatx4 acc[4];
            #pragma unroll
            for (int mt = 0; mt < 4; ++mt)
                acc[mt] = (floatx4){0.f, 0.f, 0.f, 0.f};

            #pragma unroll
            for (int ks = 0; ks < 8; ++ks) {
                const int tl = ks >> 1;
                const int j = tl >> 1, kk = tl & 1;
                const int slotj = (iy + r + j) & 3;         // row y-1+r+j
                const int icb = (ks & 1) * 32 + q * 8;
                const int cp = nt * 16 + mcol + kk + s;
                const bf16x8 b = *(const bf16x8*)&lds[slotj * LDS_ROW + cp * 64 +
                                                      (icb ^ ((cp & 7) * 8))];
                #pragma unroll
                for (int mt = 0; mt < 4; ++mt)
                    acc[mt] = __builtin_amdgcn_mfma_f32_16x16x32_bf16(
                        a[mt][ks], b, acc[mt], 0, 0, 0);
            }

            // epilogue for this nt-column: stores drain while the next nt's
            // MFMA group is still ahead in program order
            #pragma unroll
            for (int mt = 0; mt < 4; ++mt)
                #pragma unroll
                for (int rg = 0; rg < 4; ++rg)
                    op[mt * 262144 + rg * 16384 + nt * 32] =
                        act(acc[mt][rg] + bv[mt][rg]);

            // ring update, 2 cols at a time between nt phases; prefetch loads
            // have had >=1 nt-phase (~1k cyc) to land
            if (iy < 7) {
                if (nt == 1) write_row_half((iy + 3) & 3, 0, p0, p1, p2, p3);
                else if (nt == 2) write_row_half((iy + 3) & 3, 2, p0, p1, p2, p3);
            }
        }
    }
}

extern "C" void kernel_launch(void* const* d_in, const int* in_sizes, int n_in,
                              void* d_out, int out_size, void* d_ws, size_t ws_size,
                              hipStream_t stream) {
    const float* x    = (const float*)d_in[0];
    const float* wgt  = (const float*)d_in[1];
    const float* bias = (const float*)d_in[2];
    float* out = (float*)d_out;

    convt_mfma7<<<dim3(512), dim3(256), 0, stream>>>(x, wgt, bias, out);
}